// Round 11
// baseline (237.803 us; speedup 1.0000x reference)
//
#include <hip/hip_runtime.h>
#include <hip/hip_bf16.h>
#include <limits.h>

#define NSEG 200
#define STRENGTH 1e-3f
#define NB 4096                 // coarse buckets per segment
#define LOG_NB 12
#define M_TOT (NSEG * NB)
#define HCH 16384               // elements per hist block
#define SCH 8192                // elements per scatter block
#define ECHUNK 4096             // elements per emd block (512 threads)
#define ET 512
#define WCAP 4608               // window capacity (ECHUNK + 2*max_bucket)
#define BCAP 4100               // fallback staged bucket-ends capacity
#define SPAN_G 1022             // sorted-path max bucket span (4 sub-bins -> 4096 fine bins)

__device__ __forceinline__ int bucket_of(float x, float scale) {
    float t = (x + 6.0f) * scale;   // scale = NB/12
    int b = (int)floorf(t);
    b = b < 0 ? 0 : (b > NB - 1 ? NB - 1 : b);
    return b;
}

// ---- 0. segment boundaries + zero counts/segSums ----
__global__ void k_bounds(const int* __restrict__ seg, int* __restrict__ seg_starts,
                         int* __restrict__ counts, float* __restrict__ segSums, int N) {
    int stride = gridDim.x * blockDim.x;
    int tid = blockIdx.x * blockDim.x + threadIdx.x;
    for (int k = tid; k < M_TOT; k += stride) counts[k] = 0;
    for (int k = tid; k < NSEG; k += stride) segSums[k] = 0.f;
    if (tid == 0) { seg_starts[0] = 0; seg_starts[NSEG] = N; }
    const int4* s4 = (const int4*)seg;
    int N4 = N >> 2;
    for (int i = tid; i < N4; i += stride) {
        int4 s = s4[i];
        int prev = (i == 0) ? s.x : seg[i * 4 - 1];
        if (s.x != prev) seg_starts[s.x] = i * 4;
        if (s.y != s.x) seg_starts[s.y] = i * 4 + 1;
        if (s.z != s.y) seg_starts[s.z] = i * 4 + 2;
        if (s.w != s.z) seg_starts[s.w] = i * 4 + 3;
    }
}

// ---- 1. histogram of (segment, bucket) via per-block LDS hist ----
__global__ void __launch_bounds__(512)
k_hist(const float* __restrict__ x, const int* __restrict__ seg_starts,
       int* __restrict__ counts, int N, float scale) {
    __shared__ int h[2 * NB];
    __shared__ int sst[NSEG + 1];
    int t = threadIdx.x;
    for (int k = t; k < NSEG + 1; k += 512) sst[k] = seg_starts[k];
    for (int k = t; k < 2 * NB; k += 512) h[k] = 0;
    __syncthreads();
    int base = blockIdx.x * HCH;
    int lo = 0, hi = NSEG - 1;
    while (lo < hi) { int mid = (lo + hi) >> 1; if (base < sst[mid + 1]) hi = mid; else lo = mid + 1; }
    int s0 = lo, bnd = sst[lo + 1];
    const float4* x4 = (const float4*)x;
    for (int it = 0; it < HCH / (512 * 4); ++it) {
        int j = (it * 512 + t) * 4;
        int gi = base + j;
        if (gi < N) {
            float4 v = x4[(base >> 2) + it * 512 + t];
            int sel0 = (gi + 0) >= bnd ? NB : 0;
            int sel1 = (gi + 1) >= bnd ? NB : 0;
            int sel2 = (gi + 2) >= bnd ? NB : 0;
            int sel3 = (gi + 3) >= bnd ? NB : 0;
            atomicAdd(&h[sel0 + bucket_of(v.x, scale)], 1);
            atomicAdd(&h[sel1 + bucket_of(v.y, scale)], 1);
            atomicAdd(&h[sel2 + bucket_of(v.z, scale)], 1);
            atomicAdd(&h[sel3 + bucket_of(v.w, scale)], 1);
        }
    }
    __syncthreads();
    for (int k = t; k < 2 * NB; k += 512) {
        int c = h[k];
        if (c > 0) atomicAdd(&counts[(s0 + (k >= NB)) * NB + (k & (NB - 1))], c);
    }
}

// ---- 2. scan over M_TOT counters ----
__global__ void k_scan_partial(const int* __restrict__ counts, int* __restrict__ partials, int M) {
    __shared__ int sdata[256];
    int base = blockIdx.x * 2048;
    int sum = 0;
    for (int k = threadIdx.x; k < 2048; k += 256) {
        int idx = base + k;
        sum += (idx < M) ? counts[idx] : 0;
    }
    sdata[threadIdx.x] = sum;
    __syncthreads();
    for (int off = 128; off > 0; off >>= 1) {
        if (threadIdx.x < off) sdata[threadIdx.x] += sdata[threadIdx.x + off];
        __syncthreads();
    }
    if (threadIdx.x == 0) partials[blockIdx.x] = sdata[0];
}

__global__ void k_scan_final(const int* __restrict__ counts, const int* __restrict__ partials,
                             int* __restrict__ cursor, int* __restrict__ seg_ends, int M) {
    __shared__ int tile[2048];
    __shared__ int sa[256], sb[256];
    int t = threadIdx.x;
    int base = blockIdx.x * 2048;
    int c = 0;
    for (int k = t; k < blockIdx.x; k += 256) c += partials[k];
    sa[t] = c;
    __syncthreads();
    for (int off = 128; off > 0; off >>= 1) {
        if (t < off) sa[t] += sa[t + off];
        __syncthreads();
    }
    int gbase = sa[0];
    __syncthreads();
    for (int k = t; k < 2048; k += 256) {
        int idx = base + k;
        tile[k] = (idx < M) ? counts[idx] : 0;
    }
    __syncthreads();
    int loc[8]; int run = 0;
    for (int k = 0; k < 8; ++k) { loc[k] = run; run += tile[t * 8 + k]; }
    int v = run;
    int* src = sa; int* dst = sb;
    src[t] = v;
    __syncthreads();
    for (int off = 1; off < 256; off <<= 1) {
        int w = src[t] + ((t >= off) ? src[t - off] : 0);
        dst[t] = w;
        __syncthreads();
        int* tmp = src; src = dst; dst = tmp;
    }
    int texcl = src[t] - v;
    for (int k = 0; k < 8; ++k) {
        int idx = base + t * 8 + k;
        if (idx < M) {
            int excl = gbase + texcl + loc[k];
            cursor[idx] = excl;
            if (((idx + 1) & (NB - 1)) == 0)
                seg_ends[((idx + 1) >> LOG_NB) - 1] = excl + tile[t * 8 + k];
        }
    }
}

// ---- 3. scatter; (g,lr) kept in registers (no second x read) ----
__global__ void __launch_bounds__(512)
k_scatter(const float* __restrict__ x, const int* __restrict__ seg_starts,
          int* __restrict__ cursor, float* __restrict__ sx, int N, float scale) {
    __shared__ int h[2 * NB];
    __shared__ int sst[NSEG + 1];
    int t = threadIdx.x;
    for (int k = t; k < NSEG + 1; k += 512) sst[k] = seg_starts[k];
    for (int k = t; k < 2 * NB; k += 512) h[k] = 0;
    __syncthreads();
    int base = blockIdx.x * SCH;
    int lo = 0, hi = NSEG - 1;
    while (lo < hi) { int mid = (lo + hi) >> 1; if (base < sst[mid + 1]) hi = mid; else lo = mid + 1; }
    int s0 = lo, bnd = sst[lo + 1];
    const float4* x4 = (const float4*)x;
    float vv[16]; unsigned pk[16];
    // pass 1: compute (g, local rank), keep in VGPRs
    #pragma unroll
    for (int it = 0; it < SCH / (512 * 4); ++it) {
        int j = (it * 512 + t) * 4;
        int gi = base + j;
        float4 v = x4[(base >> 2) + it * 512 + t];
        int g0 = ((gi + 0) >= bnd ? NB : 0) + bucket_of(v.x, scale);
        int g1 = ((gi + 1) >= bnd ? NB : 0) + bucket_of(v.y, scale);
        int g2 = ((gi + 2) >= bnd ? NB : 0) + bucket_of(v.z, scale);
        int g3 = ((gi + 3) >= bnd ? NB : 0) + bucket_of(v.w, scale);
        vv[it * 4 + 0] = v.x; pk[it * 4 + 0] = ((unsigned)g0 << 14) | (unsigned)atomicAdd(&h[g0], 1);
        vv[it * 4 + 1] = v.y; pk[it * 4 + 1] = ((unsigned)g1 << 14) | (unsigned)atomicAdd(&h[g1], 1);
        vv[it * 4 + 2] = v.z; pk[it * 4 + 2] = ((unsigned)g2 << 14) | (unsigned)atomicAdd(&h[g2], 1);
        vv[it * 4 + 3] = v.w; pk[it * 4 + 3] = ((unsigned)g3 << 14) | (unsigned)atomicAdd(&h[g3], 1);
    }
    __syncthreads();
    // reserve: h[k] becomes global base for this block's (seg,bucket) group
    for (int k = t; k < 2 * NB; k += 512) {
        int c = h[k];
        if (c > 0) h[k] = atomicAdd(&cursor[(s0 + (k >= NB)) * NB + (k & (NB - 1))], c);
    }
    __syncthreads();
    // pass 2: write from registers
    #pragma unroll
    for (int i = 0; i < 16; ++i) {
        unsigned g = pk[i] >> 14, lr = pk[i] & 0x3fffu;
        sx[h[g] + lr] = vv[i];
    }
}

// ---- 4. EMD: low-barrier counting-sort path + R9 fallback paths ----
// smem overlay: sorted {vwin u64[WCAP+2] | fw u32[2050] | bstart u16[1024]}
//               fallback {win f32[WCAP+8] | bends i32[BCAP]}
#define SM_BYTES 47240
__global__ void __launch_bounds__(512)
k_emd(const float* __restrict__ sx, const float* __restrict__ y,
      const int* __restrict__ ends, const int* __restrict__ seg_ends,
      float* __restrict__ segSums, int N, float scale, float scale4) {
    __shared__ __align__(16) char smem[SM_BYTES];
    __shared__ int sEnd[NSEG];
    __shared__ int sh[5];
    __shared__ int wtot[8];
    unsigned long long* vwin = (unsigned long long*)smem;              // 36880 B
    unsigned* fw = (unsigned*)(smem + 36880);                          // 8200 B
    unsigned short* bstart = (unsigned short*)(smem + 36880 + 8200);   // 2048 B
    float* win = (float*)smem;                                         // fallback
    int* bends = (int*)(smem + 18496);                                 // fallback

    int tid = threadIdx.x;
    for (int k = tid; k < NSEG; k += ET) sEnd[k] = seg_ends[k];
    __syncthreads();
    int pbase = blockIdx.x * ECHUNK;
    int pend = min(pbase + ECHUNK, N);
    if (tid == 0) {
        float v = sx[pbase];
        int lo = 0, hi = NSEG - 1;
        while (lo < hi) { int mid = (lo + hi) >> 1; if (pbase < sEnd[mid]) hi = mid; else lo = mid + 1; }
        int g = lo * NB + bucket_of(v, scale);
        sh[0] = (g == 0) ? 0 : ends[g - 1];
        sh[2] = lo;
        sh[3] = g;
    }
    if (tid == ET - 1) {
        float v = sx[pend - 1];
        int lo = 0, hi = NSEG - 1;
        while (lo < hi) { int mid = (lo + hi) >> 1; if (pend - 1 < sEnd[mid]) hi = mid; else lo = mid + 1; }
        int g = lo * NB + bucket_of(v, scale);
        sh[1] = ends[g];
        sh[4] = g;
    }
    __syncthreads();
    int wlo = sh[0], whi = sh[1], s0 = sh[2], gfirst = sh[3], glast = sh[4];
    int wsz = whi - wlo;
    bool fits = wsz <= WCAP;
    bool cross = (glast >> LOG_NB) != s0;
    int nb_b = glast - gfirst + 1;
    bool sorted = fits && !cross && nb_b <= SPAN_G;

    float acc0 = 0.f, acc1 = 0.f;

    if (sorted) {
        // init: zero fine counts, load relative bucket starts
        #pragma unroll
        for (int i = 0; i < 4; ++i) fw[tid + i * ET] = 0;
        if (tid < 2) fw[2048 + tid] = (unsigned)wsz | ((unsigned)wsz << 16);
        for (int k = tid; k <= nb_b; k += ET) {
            int g = gfirst - 1 + k;
            int e = (g < 0) ? 0 : ends[g];
            bstart[k] = (unsigned short)(e - wlo);
        }
        __syncthreads();
        // build: global->reg stage + fine histogram (4 sub-bins/bucket)
        float fv[9]; unsigned fl[9];
        #pragma unroll
        for (int i = 0; i < 9; ++i) {
            int k = tid + i * ET;
            fl[i] = 0xffffffffu;
            fv[i] = 0.f;
            if (k < wsz) {
                float v = sx[wlo + k];
                fv[i] = v;
                int b = bucket_of(v, scale);
                int b4 = (int)floorf((v + 6.0f) * scale4);
                int sub = b4 - (b << 2);
                sub = sub < 0 ? 0 : (sub > 3 ? 3 : sub);
                int f = (((s0 * NB + b) - gfirst) << 2) + sub;
                unsigned shw = (f & 1) << 4;
                unsigned old = atomicAdd(&fw[f >> 1], 1u << shw);
                unsigned llo = (old >> shw) & 0xffffu;
                fl[i] = ((unsigned)f << 16) | llo;
            }
        }
        __syncthreads();
        // exclusive prefix over 4096 fine bins: per-thread 4 words + wave shfl scan + 1 LDS exchange
        unsigned wv[4]; unsigned run = 0;
        #pragma unroll
        for (int j = 0; j < 4; ++j) {
            unsigned w = fw[tid * 4 + j];
            unsigned c0 = w & 0xffffu, c1 = w >> 16;
            wv[j] = run | ((run + c0) << 16);
            run += c0 + c1;
        }
        int incl = (int)run;
        for (int off = 1; off < 64; off <<= 1) {
            int nvl = __shfl_up(incl, off, 64);
            if ((tid & 63) >= off) incl += nvl;
        }
        if ((tid & 63) == 63) wtot[tid >> 6] = incl;
        __syncthreads();
        int wbase = 0;
        int mywave = tid >> 6;
        for (int j = 0; j < mywave; ++j) wbase += wtot[j];
        unsigned base = (unsigned)(wbase + incl - (int)run);
        #pragma unroll
        for (int j = 0; j < 4; ++j) fw[tid * 4 + j] = wv[j] + (base | (base << 16));
        __syncthreads();
        // scatter u64 keys (ordered-float hi, window pos lo)
        #pragma unroll
        for (int i = 0; i < 9; ++i) {
            if (fl[i] != 0xffffffffu) {
                int f = (int)(fl[i] >> 16);
                unsigned llo = fl[i] & 0xffffu;
                unsigned pf = (fw[f >> 1] >> ((f & 1) << 4)) & 0xffffu;
                unsigned u = __float_as_uint(fv[i]);
                unsigned m = u ^ ((unsigned)((int)u >> 31) | 0x80000000u);
                int k = tid + i * ET;
                vwin[pf + llo] = ((unsigned long long)m << 32) | (unsigned)k;
            }
        }
        if (tid < 2) vwin[wsz + tid] = 0xffffffffffffffffULL;
        __syncthreads();
        // rank within fine bin + diff
        #pragma unroll
        for (int i = 0; i < 9; ++i) {
            if (fl[i] == 0xffffffffu) continue;
            int k = tid + i * ET;
            int p = wlo + k;
            if (p < pbase || p >= pend) continue;   // halo element: neighbor block's
            int f = (int)(fl[i] >> 16);
            float v = fv[i];
            unsigned u = __float_as_uint(v);
            unsigned m = u ^ ((unsigned)((int)u >> 31) | 0x80000000u);
            unsigned long long kme = ((unsigned long long)m << 32) | (unsigned)k;
            unsigned fs = (fw[f >> 1] >> ((f & 1) << 4)) & 0xffffu;
            unsigned fe = (fw[(f + 1) >> 1] >> (((f + 1) & 1) << 4)) & 0xffffu;
            int bi = f >> 2;
            unsigned b0 = fw[bi << 1] & 0xffffu;    // prefix of bucket's first fine bin
            int a2 = (int)(fs & ~1u);
            int rank = a2 - (int)b0;                // slots [a2,fs): strictly smaller keys
            for (int j = a2; j < (int)fe; j += 2) {
                ulonglong2 q = *(const ulonglong2*)&vwin[j];
                rank += (q.x < kme) + (q.y < kme);  // over-read: larger key / pad -> 0
            }
            acc0 += fabsf(v - y[wlo + (int)bstart[bi] + rank]);
        }
    } else {
        // ---- fallback: R9 medium / global paths ----
        int bcount = nb_b + 1;
        bool useB = fits && bcount <= BCAP;
        if (fits) {
            for (int k = tid; k < wsz; k += ET) win[k] = sx[wlo + k];
            if (tid < 8) win[wsz + tid] = __builtin_inff();
        }
        if (useB) {
            for (int k = tid; k < bcount; k += ET) {
                int g = gfirst - 1 + k;
                bends[k] = (g < 0) ? 0 : ends[g];
            }
        }
        __syncthreads();
        if (fits) {
            for (int e = 0; e < ECHUNK / ET; ++e) {
                int p = pbase + e * ET + tid;
                if (p >= pend) break;
                int s = s0;
                while (p >= sEnd[s]) ++s;
                int widx = p - wlo;
                float v = win[widx];
                int g = s * NB + bucket_of(v, scale);
                int start, end;
                if (useB) { start = bends[g - gfirst]; end = bends[g - gfirst + 1]; }
                else { start = (g == 0) ? 0 : ends[g - 1]; end = ends[g]; }
                int a = start - wlo, bqq = end - wlo;
                int rank = 0;
                int k = a;
                for (; k < bqq && (k & 3); ++k) { float vj = win[k]; rank += (vj < v) + ((vj == v) & (k < widx)); }
                for (; k + 3 < bqq; k += 4) {
                    float4 q = *(const float4*)&win[k];
                    rank += (q.x < v) + ((q.x == v) & (k + 0 < widx));
                    rank += (q.y < v) + ((q.y == v) & (k + 1 < widx));
                    rank += (q.z < v) + ((q.z == v) & (k + 2 < widx));
                    rank += (q.w < v) + ((q.w == v) & (k + 3 < widx));
                }
                for (; k < bqq; ++k) { float vj = win[k]; rank += (vj < v) + ((vj == v) & (k < widx)); }
                float diff = fabsf(v - y[start + rank]);
                if (s == s0) acc0 += diff;
                else if (s == s0 + 1) acc1 += diff;
                else atomicAdd(&segSums[s], diff);
            }
        } else {
            for (int e = 0; e < ECHUNK / ET; ++e) {
                int p = pbase + e * ET + tid;
                if (p >= pend) break;
                int s = s0;
                while (p >= sEnd[s]) ++s;
                float v = sx[p];
                int g = s * NB + bucket_of(v, scale);
                int start = (g == 0) ? 0 : ends[g - 1];
                int end = ends[g];
                int rank = 0;
                for (int j = start; j < end; ++j) { float vj = sx[j]; rank += (vj < v) || (vj == v && j < p); }
                float diff = fabsf(v - y[start + rank]);
                if (s == s0) acc0 += diff;
                else if (s == s0 + 1) acc1 += diff;
                else atomicAdd(&segSums[s], diff);
            }
        }
    }

    for (int off = 32; off > 0; off >>= 1) {
        acc0 += __shfl_xor(acc0, off);
        acc1 += __shfl_xor(acc1, off);
    }
    if ((tid & 63) == 0) {
        if (acc0 != 0.f) atomicAdd(&segSums[s0], acc0);
        if (acc1 != 0.f && s0 + 1 < NSEG) atomicAdd(&segSums[s0 + 1], acc1);
    }
}

// ---- 5. finalize ----
__global__ void k_final(const float* __restrict__ segSums, const int* __restrict__ seg_ends,
                        float* __restrict__ out) {
    __shared__ float red[256];
    int t = threadIdx.x;
    float acc = 0.f;
    for (int s = t; s < NSEG; s += 256) {
        int end = seg_ends[s];
        int st = (s == 0) ? 0 : seg_ends[s - 1];
        float cnt = (float)(end - st);
        acc += segSums[s] / fmaxf(cnt, 1.0f);
    }
    red[t] = acc;
    __syncthreads();
    for (int off = 128; off > 0; off >>= 1) {
        if (t < off) red[t] += red[t + off];
        __syncthreads();
    }
    if (t == 0) out[0] = red[0] * (1.0f / (float)NSEG) * STRENGTH;
}

extern "C" void kernel_launch(void* const* d_in, const int* in_sizes, int n_in,
                              void* d_out, int out_size, void* d_ws, size_t ws_size,
                              hipStream_t stream) {
    const float* x = (const float*)d_in[0];
    const float* y = (const float*)d_in[1];          // initial_sorted
    const int* seg = (const int*)d_in[2];            // segment_ids (sorted)
    int N = in_sizes[0];
    float scale = (float)NB / 12.0f;
    float scale4 = (float)NB * 4.0f / 12.0f;

    char* ws = (char*)d_ws;
    float* sx        = (float*)ws;                        // N floats
    int*   counts    = (int*)(ws + (size_t)N * 4);        // M_TOT ints
    int*   cursor    = counts + M_TOT;                    // M_TOT ints
    int*   partials  = cursor + M_TOT;                    // <=1024 ints
    float* segSums   = (float*)(partials + 1024);         // NSEG floats
    int*   seg_ends  = (int*)(segSums + NSEG);            // NSEG ints
    int*   seg_starts= seg_ends + NSEG;                   // NSEG+1 ints

    int nb = (M_TOT + 2047) / 2048;    // = 400
    int nch_h = (N + HCH - 1) / HCH;
    int nch_s = (N + SCH - 1) / SCH;

    k_bounds<<<512, 256, 0, stream>>>(seg, seg_starts, counts, segSums, N);
    k_hist<<<nch_h, 512, 0, stream>>>(x, seg_starts, counts, N, scale);
    k_scan_partial<<<nb, 256, 0, stream>>>(counts, partials, M_TOT);
    k_scan_final<<<nb, 256, 0, stream>>>(counts, partials, cursor, seg_ends, M_TOT);
    k_scatter<<<nch_s, 512, 0, stream>>>(x, seg_starts, cursor, sx, N, scale);
    k_emd<<<(N + ECHUNK - 1) / ECHUNK, ET, 0, stream>>>(sx, y, cursor, seg_ends, segSums, N, scale, scale4);
    k_final<<<1, 256, 0, stream>>>(segSums, seg_ends, (float*)d_out);
}